// Round 1
// baseline (14411.113 us; speedup 1.0000x reference)
//
#include <hip/hip_runtime.h>
#include <math.h>

#define NPTS 4096
#define CO   256
#define CI   128
#define BB   4
#define DQ   64
#define LL   4

// ---------------------------------------------------------------------------
// GEMM: Y[b,d,n] = sum_c W[d,c] * X[b,c,n] (+ bias[d])
// IN_T:  X stored as [b][n][c] (inner stride on c, row stride C)
// OUT_T: Y stored as [b][n][d] (row stride Dtot)
template<bool IN_T, bool OUT_T, bool BIAS>
__global__ __launch_bounds__(256) void gemm_k(
    const float* __restrict__ X, long xbs,
    const float* __restrict__ W, const float* __restrict__ bias,
    int C, int Dtot, float* __restrict__ Y, long ybs)
{
  const int n0 = blockIdx.x * 64;
  const int d0 = blockIdx.y * 64;
  const int b  = blockIdx.z;
  const int t  = threadIdx.x;
  const int tn = t & 63;
  const int tg = t >> 6;

  __shared__ float xs[64][65];   // [cc][nn]
  __shared__ float ws[64][68];   // [cc][dd], pad 68 keeps rows 16B aligned

  float acc[16];
#pragma unroll
  for (int i = 0; i < 16; ++i) acc[i] = 0.f;

  for (int c0 = 0; c0 < C; c0 += 64) {
    if (!IN_T) {
#pragma unroll
      for (int r = 0; r < 16; ++r) {
        const int cc = tg * 16 + r;
        xs[cc][tn] = X[(long)b * xbs + (long)(c0 + cc) * NPTS + (n0 + tn)];
      }
    } else {
#pragma unroll
      for (int r = 0; r < 16; ++r) {
        const int nn = tg * 16 + r;
        xs[tn][nn] = X[(long)b * xbs + (long)(n0 + nn) * C + (c0 + tn)];
      }
    }
#pragma unroll
    for (int k = 0; k < 16; ++k) {
      const int e = k * 256 + t;
      const int dd = e >> 6, cc = e & 63;
      ws[cc][dd] = W[(long)(d0 + dd) * C + (c0 + cc)];
    }
    __syncthreads();
#pragma unroll 4
    for (int cc = 0; cc < 64; ++cc) {
      const float xv = xs[cc][tn];
      const float4* wr = (const float4*)&ws[cc][tg * 16];
#pragma unroll
      for (int u = 0; u < 4; ++u) {
        const float4 w4 = wr[u];
        acc[u*4+0] = fmaf(w4.x, xv, acc[u*4+0]);
        acc[u*4+1] = fmaf(w4.y, xv, acc[u*4+1]);
        acc[u*4+2] = fmaf(w4.z, xv, acc[u*4+2]);
        acc[u*4+3] = fmaf(w4.w, xv, acc[u*4+3]);
      }
    }
    __syncthreads();
  }

  if (BIAS) {
#pragma unroll
    for (int i = 0; i < 16; ++i) acc[i] += bias[d0 + tg * 16 + i];
  }
  if (!OUT_T) {
#pragma unroll
    for (int i = 0; i < 16; ++i)
      Y[(long)b * ybs + (long)(d0 + tg * 16 + i) * NPTS + (n0 + tn)] = acc[i];
  } else {
    float4* yp = (float4*)&Y[(long)b * ybs + (long)(n0 + tn) * Dtot + d0 + tg * 16];
#pragma unroll
    for (int u = 0; u < 4; ++u)
      yp[u] = make_float4(acc[u*4+0], acc[u*4+1], acc[u*4+2], acc[u*4+3]);
  }
}

// ---------------------------------------------------------------------------
// BN training-mode stats per channel over (B, N)
__global__ __launch_bounds__(256) void bnstats_k(
    const float* __restrict__ X, long xbs,
    float* __restrict__ mean, float* __restrict__ rstd)
{
  const int c = blockIdx.x, t = threadIdx.x;
  float s = 0.f, s2 = 0.f;
  for (int b = 0; b < BB; ++b) {
    const float* p = X + (long)b * xbs + (long)c * NPTS;
    for (int n = t; n < NPTS; n += 256) { const float v = p[n]; s += v; s2 += v * v; }
  }
#pragma unroll
  for (int o = 32; o > 0; o >>= 1) { s += __shfl_down(s, o); s2 += __shfl_down(s2, o); }
  __shared__ float a1[4], a2[4];
  if ((t & 63) == 0) { a1[t >> 6] = s; a2[t >> 6] = s2; }
  __syncthreads();
  if (t == 0) {
    const float S  = a1[0] + a1[1] + a1[2] + a1[3];
    const float S2 = a2[0] + a2[1] + a2[2] + a2[3];
    const float m  = S / (float)(BB * NPTS);
    const float v  = S2 / (float)(BB * NPTS) - m * m;
    mean[c] = m;
    rstd[c] = rsqrtf(v + 1e-5f);
  }
}

// BN normalize + affine + ReLU (elementwise, in/out may alias)
__global__ __launch_bounds__(256) void bnrelu_k(
    const float* __restrict__ X, long xbs,
    const float* __restrict__ mean, const float* __restrict__ rstd,
    const float* __restrict__ g, const float* __restrict__ be,
    float* __restrict__ Y, long ybs)
{
  const long total = (long)BB * CO * NPTS;
  for (long idx = (long)blockIdx.x * 256 + threadIdx.x; idx < total;
       idx += (long)gridDim.x * 256) {
    const int n = (int)(idx & (NPTS - 1));
    const int c = (int)((idx >> 12) & (CO - 1));
    const int b = (int)(idx >> 20);
    const float v = X[(long)b * xbs + (long)c * NPTS + n];
    const float o = (v - mean[c]) * rstd[c] * g[c] + be[c];
    Y[(long)b * ybs + (long)c * NPTS + n] = fmaxf(o, 0.f);
  }
}

// ---------------------------------------------------------------------------
// Pass 1: per-row softmax stats of S = K^T K (row n: max_m, sum_m exp)
__global__ __launch_bounds__(256) void rowstats_k(
    const float* __restrict__ Kd, float* __restrict__ rmax, float* __restrict__ rsum)
{
  const int n0 = blockIdx.x * 64;
  const int b  = blockIdx.y;
  const int t = threadIdx.x, tr = t & 63, tg = t >> 6;

  __shared__ float Kn[64][64];   // [d][n] block rows
  __shared__ float Km[64][68];   // [d][m] iterated cols
  __shared__ float pm[4][64], ps[4][64];

#pragma unroll
  for (int r = 0; r < 16; ++r)
    Kn[tg * 16 + r][tr] = Kd[((long)b * DQ + tg * 16 + r) * NPTS + (n0 + tr)];

  float mx = -INFINITY, sm = 0.f;

  for (int m0 = 0; m0 < NPTS; m0 += 64) {
    __syncthreads();
#pragma unroll
    for (int r = 0; r < 16; ++r)
      Km[tg * 16 + r][tr] = Kd[((long)b * DQ + tg * 16 + r) * NPTS + (m0 + tr)];
    __syncthreads();

    float s[16];
#pragma unroll
    for (int i = 0; i < 16; ++i) s[i] = 0.f;
#pragma unroll 4
    for (int d = 0; d < 64; ++d) {
      const float kn = Kn[d][tr];
      const float4* kr = (const float4*)&Km[d][tg * 16];
#pragma unroll
      for (int u = 0; u < 4; ++u) {
        const float4 k4 = kr[u];
        s[u*4+0] = fmaf(kn, k4.x, s[u*4+0]);
        s[u*4+1] = fmaf(kn, k4.y, s[u*4+1]);
        s[u*4+2] = fmaf(kn, k4.z, s[u*4+2]);
        s[u*4+3] = fmaf(kn, k4.w, s[u*4+3]);
      }
    }
    float tm = s[0];
#pragma unroll
    for (int i = 1; i < 16; ++i) tm = fmaxf(tm, s[i]);
    const float m2 = fmaxf(mx, tm);
    float add = 0.f;
#pragma unroll
    for (int i = 0; i < 16; ++i) add += __expf(s[i] - m2);
    sm = sm * __expf(mx - m2) + add;
    mx = m2;
  }

  pm[tg][tr] = mx; ps[tg][tr] = sm;
  __syncthreads();
  if (t < 64) {
    const float M = fmaxf(fmaxf(pm[0][t], pm[1][t]), fmaxf(pm[2][t], pm[3][t]));
    const float S = ps[0][t] * __expf(pm[0][t] - M) + ps[1][t] * __expf(pm[1][t] - M)
                  + ps[2][t] * __expf(pm[2][t] - M) + ps[3][t] * __expf(pm[3][t] - M);
    rmax[(long)b * NPTS + n0 + t] = M;
    rsum[(long)b * NPTS + n0 + t] = S;
  }
}

// ---------------------------------------------------------------------------
// Pass 2: per m-tile: recompute S tile, P = exp(S - rmax[n]) / rsum[n],
// Y[c,m] += V[c,n] P[n,m], colsum[m] += P[n,m]; write nf^T = Y/(1e-9+colsum)
__global__ __launch_bounds__(256) void pass2_k(
    const float* __restrict__ Kd, const float* __restrict__ Vt,
    const float* __restrict__ rmax, const float* __restrict__ rsum,
    float* __restrict__ NFt, long nbs)
{
  const int m0 = blockIdx.x * 64;
  const int b  = blockIdx.y;
  const int t = threadIdx.x, tr = t & 63, tg = t >> 6;

  __shared__ float Km[64][68];   // [d][m] block-fixed
  __shared__ float Kn[64][64];   // [d][n] iterated
  __shared__ float Ps[64][68];   // [nn][mm]
  __shared__ float csum[64];

  float acc[64];
#pragma unroll
  for (int i = 0; i < 64; ++i) acc[i] = 0.f;
  float cs[16];
#pragma unroll
  for (int i = 0; i < 16; ++i) cs[i] = 0.f;

#pragma unroll
  for (int r = 0; r < 16; ++r)
    Km[tg * 16 + r][tr] = Kd[((long)b * DQ + tg * 16 + r) * NPTS + (m0 + tr)];

  for (int n0 = 0; n0 < NPTS; n0 += 64) {
    __syncthreads();
#pragma unroll
    for (int r = 0; r < 16; ++r)
      Kn[tg * 16 + r][tr] = Kd[((long)b * DQ + tg * 16 + r) * NPTS + (n0 + tr)];
    __syncthreads();

    // S tile: row = n0+tr, cols m0 + tg*16 + i
    float s[16];
#pragma unroll
    for (int i = 0; i < 16; ++i) s[i] = 0.f;
#pragma unroll 4
    for (int d = 0; d < 64; ++d) {
      const float kn = Kn[d][tr];
      const float4* kr = (const float4*)&Km[d][tg * 16];
#pragma unroll
      for (int u = 0; u < 4; ++u) {
        const float4 k4 = kr[u];
        s[u*4+0] = fmaf(kn, k4.x, s[u*4+0]);
        s[u*4+1] = fmaf(kn, k4.y, s[u*4+1]);
        s[u*4+2] = fmaf(kn, k4.z, s[u*4+2]);
        s[u*4+3] = fmaf(kn, k4.w, s[u*4+3]);
      }
    }
    const float rm = rmax[(long)b * NPTS + n0 + tr];
    const float ri = 1.f / rsum[(long)b * NPTS + n0 + tr];
#pragma unroll
    for (int i = 0; i < 16; ++i) {
      const float p = __expf(s[i] - rm) * ri;
      Ps[tr][tg * 16 + i] = p;
      cs[i] += p;
    }
    __syncthreads();

    // PV: thread owns channel c = t; acc[mm] += V^T[n][c] * P[n][mm]
    const float* vp = Vt + ((long)b * NPTS + n0) * CO + t;
#pragma unroll 2
    for (int nn = 0; nn < 64; ++nn) {
      const float v = vp[(long)nn * CO];
      const float4* pr = (const float4*)&Ps[nn][0];
#pragma unroll
      for (int u = 0; u < 16; ++u) {
        const float4 p4 = pr[u];
        acc[u*4+0] = fmaf(v, p4.x, acc[u*4+0]);
        acc[u*4+1] = fmaf(v, p4.y, acc[u*4+1]);
        acc[u*4+2] = fmaf(v, p4.z, acc[u*4+2]);
        acc[u*4+3] = fmaf(v, p4.w, acc[u*4+3]);
      }
    }
  }

  // colsum: reduce cs over the 64 lanes of each wave (lanes = rows tr)
#pragma unroll
  for (int i = 0; i < 16; ++i) {
#pragma unroll
    for (int o = 32; o > 0; o >>= 1) cs[i] += __shfl_down(cs[i], o);
  }
  if (tr == 0) {
#pragma unroll
    for (int i = 0; i < 16; ++i) csum[tg * 16 + i] = cs[i];
  }
  __syncthreads();

#pragma unroll
  for (int mm = 0; mm < 64; ++mm)
    NFt[(long)b * nbs + (long)(m0 + mm) * CO + t] = acc[mm] / (1e-9f + csum[mm]);
}

// ---------------------------------------------------------------------------
// off^T[b][n][c] = x[b][c][n] - nf^T[b][n][c]   (LDS transpose of x)
__global__ __launch_bounds__(256) void offsub_k(
    const float* __restrict__ X, long xbs,
    const float* __restrict__ NFt, long nbs,
    float* __restrict__ OFFt, long obs)
{
  const int n0 = blockIdx.x * 64;
  const int c0 = blockIdx.y * 64;
  const int b  = blockIdx.z;
  const int t = threadIdx.x, tl = t & 63, tg = t >> 6;
  __shared__ float xs[64][65];  // [cc][nn]
#pragma unroll
  for (int r = 0; r < 16; ++r) {
    const int cc = tg * 16 + r;
    xs[cc][tl] = X[(long)b * xbs + (long)(c0 + cc) * NPTS + (n0 + tl)];
  }
  __syncthreads();
#pragma unroll
  for (int r = 0; r < 16; ++r) {
    const int nn = tg * 16 + r;
    OFFt[(long)b * obs + (long)(n0 + nn) * CO + (c0 + tl)] =
        xs[tl][nn] - NFt[(long)b * nbs + (long)(n0 + nn) * CO + (c0 + tl)];
  }
}

// ---------------------------------------------------------------------------
extern "C" void kernel_launch(void* const* d_in, const int* in_sizes, int n_in,
                              void* d_out, int out_size, void* d_ws, size_t ws_size,
                              hipStream_t stream)
{
  const float* feat = (const float*)d_in[0];
  const float* w1   = (const float*)d_in[1];
  const float* g1   = (const float*)d_in[2];
  const float* b1   = (const float*)d_in[3];
  const float* w2   = (const float*)d_in[4];
  const float* g2   = (const float*)d_in[5];
  const float* b2   = (const float*)d_in[6];
  const float* qkw  = (const float*)d_in[7];
  const float* vw   = (const float*)d_in[8];
  const float* vb   = (const float*)d_in[9];
  const float* tw   = (const float*)d_in[10];
  const float* tb   = (const float*)d_in[11];
  const float* bng  = (const float*)d_in[12];
  const float* bnb  = (const float*)d_in[13];

  float* out = (float*)d_out;
  float* wsf = (float*)d_ws;

  // workspace layout (~21 MB)
  float* Kbuf = wsf;                                   // [B][DQ][N]
  float* Vbuf = Kbuf + (long)BB * DQ * NPTS;           // [B][N][CO]  (V^T, then off^T)
  float* rmax = Vbuf + (long)BB * NPTS * CO;           // [B][N]
  float* rsum = rmax + (long)BB * NPTS;                // [B][N]
  float* mean = rsum + (long)BB * NPTS;                // [CO]
  float* rstd = mean + CO;                             // [CO]

  const long OBS = (long)LL * CO * NPTS;  // d_out batch stride
  // alias not-yet-final d_out slice regions as scratch (each fully rewritten
  // before its validated values are produced):
  float* h1 = out + (long)2 * CO * NPTS;  // stem pre/post-BN h1 -> slice 2 region
  float* x0 = out + (long)1 * CO * NPTS;  // stem output x0     -> slice 1 region

  const dim3 blk(256);

  // ---- stem ----
  gemm_k<false,false,false><<<dim3(NPTS/64, CO/64, BB), blk, 0, stream>>>(
      feat, (long)CI * NPTS, w1, nullptr, CI, CO, h1, OBS);
  bnstats_k<<<dim3(CO), blk, 0, stream>>>(h1, OBS, mean, rstd);
  bnrelu_k<<<dim3(2048), blk, 0, stream>>>(h1, OBS, mean, rstd, g1, b1, h1, OBS);
  gemm_k<false,false,false><<<dim3(NPTS/64, CO/64, BB), blk, 0, stream>>>(
      h1, OBS, w2, nullptr, CO, CO, x0, OBS);
  bnstats_k<<<dim3(CO), blk, 0, stream>>>(x0, OBS, mean, rstd);
  bnrelu_k<<<dim3(2048), blk, 0, stream>>>(x0, OBS, mean, rstd, g2, b2, x0, OBS);

  // ---- stacked offset attention ----
  const float* x = x0;
  for (int l = 0; l < LL; ++l) {
    float* nft = out + (long)l * CO * NPTS;  // slice l region: nf^T, then t, then final
    gemm_k<false,false,false><<<dim3(NPTS/64, DQ/64, BB), blk, 0, stream>>>(
        x, OBS, qkw + (long)l * DQ * CO, nullptr, CO, DQ, Kbuf, (long)DQ * NPTS);
    gemm_k<false,true,true><<<dim3(NPTS/64, CO/64, BB), blk, 0, stream>>>(
        x, OBS, vw + (long)l * CO * CO, vb + (long)l * CO, CO, CO, Vbuf, (long)NPTS * CO);
    rowstats_k<<<dim3(NPTS/64, BB), blk, 0, stream>>>(Kbuf, rmax, rsum);
    pass2_k<<<dim3(NPTS/64, BB), blk, 0, stream>>>(Kbuf, Vbuf, rmax, rsum, nft, OBS);
    offsub_k<<<dim3(NPTS/64, CO/64, BB), blk, 0, stream>>>(
        x, OBS, nft, OBS, Vbuf, (long)NPTS * CO);
    gemm_k<true,false,true><<<dim3(NPTS/64, CO/64, BB), blk, 0, stream>>>(
        Vbuf, (long)NPTS * CO, tw + (long)l * CO * CO, tb + (long)l * CO, CO, CO, nft, OBS);
    bnstats_k<<<dim3(CO), blk, 0, stream>>>(nft, OBS, mean, rstd);
    bnrelu_k<<<dim3(2048), blk, 0, stream>>>(
        nft, OBS, mean, rstd, bng + (long)l * CO, bnb + (long)l * CO, nft, OBS);
    x = nft;
  }
}

// Round 2
// 1497.810 us; speedup vs baseline: 9.6215x; 9.6215x over previous
//
#include <hip/hip_runtime.h>
#include <hip/hip_bf16.h>
#include <math.h>

#define NPTS 4096
#define CO   256
#define CI   128
#define BB   4
#define DQ   64
#define LL   4
#define PSTR 72   // shorts; 144B row stride keeps 16B alignment for b128 reads

typedef __attribute__((ext_vector_type(8))) short bf16x8;
typedef __attribute__((ext_vector_type(4))) float f32x4;

#define MFMA16(a,b,c) __builtin_amdgcn_mfma_f32_16x16x32_bf16((a),(b),(c),0,0,0)

__device__ __forceinline__ short fb(float x) {
  __hip_bfloat16 h = __float2bfloat16(x);
  return __builtin_bit_cast(short, h);
}
__device__ __forceinline__ float bf(short s) {
  unsigned u = ((unsigned)(unsigned short)s) << 16;
  return __builtin_bit_cast(float, u);
}
__device__ __forceinline__ bf16x8 cvt8(const float* __restrict__ p) {
  const float4 a = *(const float4*)p;
  const float4 b = *(const float4*)(p + 4);
  bf16x8 r;
  r[0] = fb(a.x); r[1] = fb(a.y); r[2] = fb(a.z); r[3] = fb(a.w);
  r[4] = fb(b.x); r[5] = fb(b.y); r[6] = fb(b.z); r[7] = fb(b.w);
  return r;
}

// ---------------------------------------------------------------------------
// fp32 [b][C][N] -> bf16 [b][N][C] transpose-convert
__global__ __launch_bounds__(256) void tcvt_k(
    const float* __restrict__ X, long xbs, int C, short* __restrict__ XT)
{
  const int n0 = blockIdx.x * 64, c0 = blockIdx.y * 64, b = blockIdx.z;
  const int t = threadIdx.x, tl = t & 63, tg = t >> 6;
  __shared__ float xs[64][65];
#pragma unroll
  for (int r = 0; r < 16; ++r) {
    const int cc = tg * 16 + r;
    xs[cc][tl] = X[(long)b * xbs + (long)(c0 + cc) * NPTS + n0 + tl];
  }
  __syncthreads();
#pragma unroll
  for (int r = 0; r < 16; ++r) {
    const int nn = tg * 16 + r;
    XT[((long)b * NPTS + n0 + nn) * C + c0 + tl] = fb(xs[tl][nn]);
  }
}

// ---------------------------------------------------------------------------
// conv_a: Y[b][d][n] = sum_c W[d][c] * XT[b][n][c] (+bias). A=W, B=XT.
template<bool OBF, bool BIAS>
__global__ __launch_bounds__(256) void conv_a(
    const short* __restrict__ XT, int C,
    const float* __restrict__ W, const float* __restrict__ bias,
    void* __restrict__ Yv, long ybs)
{
  const int n0 = blockIdx.x * 64, d0 = blockIdx.y * 64, b = blockIdx.z;
  const int tid = threadIdx.x, w = tid >> 6, l = tid & 63, lg = l >> 4, lr = l & 15;
  const short* xb = XT + (long)b * NPTS * C;
  f32x4 acc[4];
#pragma unroll
  for (int i = 0; i < 4; ++i) acc[i] = (f32x4){0.f, 0.f, 0.f, 0.f};
  const int dr = d0 + w * 16 + lr;
  for (int kc = 0; kc < C; kc += 32) {
    const bf16x8 af = cvt8(&W[(long)dr * C + kc + lg * 8]);
#pragma unroll
    for (int ni = 0; ni < 4; ++ni) {
      const bf16x8 bfx = *(const bf16x8*)&xb[(long)(n0 + ni * 16 + lr) * C + kc + lg * 8];
      acc[ni] = MFMA16(af, bfx, acc[ni]);
    }
  }
  float bv[4] = {0.f, 0.f, 0.f, 0.f};
  if (BIAS) {
    const float4 b4 = *(const float4*)&bias[d0 + w * 16 + lg * 4];
    bv[0] = b4.x; bv[1] = b4.y; bv[2] = b4.z; bv[3] = b4.w;
  }
  const int db = d0 + w * 16 + lg * 4;
#pragma unroll
  for (int ni = 0; ni < 4; ++ni) {
    const int n = n0 + ni * 16 + lr;
#pragma unroll
    for (int j = 0; j < 4; ++j) {
      const float o = acc[ni][j] + bv[j];
      if constexpr (OBF) {
        ((short*)Yv)[(long)b * ybs + (long)(db + j) * NPTS + n] = fb(o);
      } else {
        ((float*)Yv)[(long)b * ybs + (long)(db + j) * NPTS + n] = o;
      }
    }
  }
}

// ---------------------------------------------------------------------------
// conv_b: KT[b][n][d] = sum_c XT[b][n][c] * W[d][c]. A=XT, B=W. Dtot=64.
__global__ __launch_bounds__(256) void conv_b(
    const short* __restrict__ XT, const float* __restrict__ W,
    short* __restrict__ KTo)
{
  const int n0 = blockIdx.x * 64, b = blockIdx.y;
  const int tid = threadIdx.x, w = tid >> 6, l = tid & 63, lg = l >> 4, lr = l & 15;
  const short* xb = XT + (long)b * NPTS * CO;
  f32x4 acc[4];
#pragma unroll
  for (int i = 0; i < 4; ++i) acc[i] = (f32x4){0.f, 0.f, 0.f, 0.f};
  const long nr = n0 + w * 16 + lr;
  for (int kc = 0; kc < CO; kc += 32) {
    const bf16x8 af = *(const bf16x8*)&xb[nr * CO + kc + lg * 8];
#pragma unroll
    for (int di = 0; di < 4; ++di) {
      const bf16x8 wf = cvt8(&W[(long)(di * 16 + lr) * CO + kc + lg * 8]);
      acc[di] = MFMA16(af, wf, acc[di]);
    }
  }
  short* Ko = KTo + (long)b * NPTS * DQ;
  const int nb = n0 + w * 16 + lg * 4;
#pragma unroll
  for (int j = 0; j < 4; ++j) {
#pragma unroll
    for (int di = 0; di < 4; ++di)
      Ko[(long)(nb + j) * DQ + di * 16 + lr] = fb(acc[di][j]);
  }
}

// ---------------------------------------------------------------------------
// BN stats + normalize (unchanged fp32)
__global__ __launch_bounds__(256) void bnstats_k(
    const float* __restrict__ X, long xbs,
    float* __restrict__ mean, float* __restrict__ rstd)
{
  const int c = blockIdx.x, t = threadIdx.x;
  float s = 0.f, s2 = 0.f;
  for (int b = 0; b < BB; ++b) {
    const float* p = X + (long)b * xbs + (long)c * NPTS;
    for (int n = t; n < NPTS; n += 256) { const float v = p[n]; s += v; s2 += v * v; }
  }
#pragma unroll
  for (int o = 32; o > 0; o >>= 1) { s += __shfl_down(s, o); s2 += __shfl_down(s2, o); }
  __shared__ float a1[4], a2[4];
  if ((t & 63) == 0) { a1[t >> 6] = s; a2[t >> 6] = s2; }
  __syncthreads();
  if (t == 0) {
    const float S  = a1[0] + a1[1] + a1[2] + a1[3];
    const float S2 = a2[0] + a2[1] + a2[2] + a2[3];
    const float m  = S / (float)(BB * NPTS);
    const float v  = S2 / (float)(BB * NPTS) - m * m;
    mean[c] = m;
    rstd[c] = rsqrtf(v + 1e-5f);
  }
}

__global__ __launch_bounds__(256) void bnrelu_k(
    const float* __restrict__ X, long xbs,
    const float* __restrict__ mean, const float* __restrict__ rstd,
    const float* __restrict__ g, const float* __restrict__ be,
    float* __restrict__ Y, long ybs)
{
  const long total = (long)BB * CO * NPTS;
  for (long idx = (long)blockIdx.x * 256 + threadIdx.x; idx < total;
       idx += (long)gridDim.x * 256) {
    const int n = (int)(idx & (NPTS - 1));
    const int c = (int)((idx >> 12) & (CO - 1));
    const int b = (int)(idx >> 20);
    const float v = X[(long)b * xbs + (long)c * NPTS + n];
    const float o = (v - mean[c]) * rstd[c] * g[c] + be[c];
    Y[(long)b * ybs + (long)c * NPTS + n] = fmaxf(o, 0.f);
  }
}

// ---------------------------------------------------------------------------
// pass1: per-row softmax stats of S = K^T K over an m-chunk (MFMA)
#define ONL(MX, SM, SV) { const float m2_ = fmaxf(MX, SV); \
  SM = SM * __expf(MX - m2_) + __expf(SV - m2_); MX = m2_; }
#define MRG(MX, SM, OFF) { const float om_ = __shfl_xor(MX, OFF); \
  const float os_ = __shfl_xor(SM, OFF); \
  const float m2_ = fmaxf(MX, om_); \
  SM = SM * __expf(MX - m2_) + os_ * __expf(om_ - m2_); MX = m2_; }

__global__ __launch_bounds__(256) void rowstats_mfma(
    const short* __restrict__ KT, float* __restrict__ pmax, float* __restrict__ psum)
{
  const int n0 = blockIdx.x * 64;
  const int chunk = blockIdx.y;
  const int b = blockIdx.z;
  const int tid = threadIdx.x, w = tid >> 6, l = tid & 63, lg = l >> 4, lr = l & 15;
  const short* Kb = KT + (long)b * NPTS * DQ;
  const int nr = n0 + w * 16 + lr;
  const bf16x8 a0 = *(const bf16x8*)&Kb[(long)nr * DQ + lg * 8];
  const bf16x8 a1 = *(const bf16x8*)&Kb[(long)nr * DQ + 32 + lg * 8];

  float mx0 = -INFINITY, mx1 = -INFINITY, mx2 = -INFINITY, mx3 = -INFINITY;
  float sm0 = 0.f, sm1 = 0.f, sm2 = 0.f, sm3 = 0.f;

  const int mc = chunk * (NPTS / 4);
  for (int m0 = mc; m0 < mc + NPTS / 4; m0 += 16) {
    const bf16x8 b0 = *(const bf16x8*)&Kb[(long)(m0 + lr) * DQ + lg * 8];
    const bf16x8 b1 = *(const bf16x8*)&Kb[(long)(m0 + lr) * DQ + 32 + lg * 8];
    f32x4 s = {0.f, 0.f, 0.f, 0.f};
    s = MFMA16(a0, b0, s);
    s = MFMA16(a1, b1, s);
    ONL(mx0, sm0, s[0]); ONL(mx1, sm1, s[1]);
    ONL(mx2, sm2, s[2]); ONL(mx3, sm3, s[3]);
  }
#pragma unroll
  for (int off = 1; off < 16; off <<= 1) {
    MRG(mx0, sm0, off); MRG(mx1, sm1, off);
    MRG(mx2, sm2, off); MRG(mx3, sm3, off);
  }
  if (lr == 0) {
    const long base = ((long)chunk * BB + b) * NPTS + n0 + w * 16 + lg * 4;
    pmax[base + 0] = mx0; pmax[base + 1] = mx1; pmax[base + 2] = mx2; pmax[base + 3] = mx3;
    psum[base + 0] = sm0; psum[base + 1] = sm1; psum[base + 2] = sm2; psum[base + 3] = sm3;
  }
}

__global__ __launch_bounds__(256) void combine_k(
    const float* __restrict__ pmax, const float* __restrict__ psum,
    float* __restrict__ rmax, float* __restrict__ rinv)
{
  const long i = (long)blockIdx.x * 256 + threadIdx.x;
  const long st = (long)BB * NPTS;
  float m = pmax[i];
  m = fmaxf(m, pmax[st + i]); m = fmaxf(m, pmax[2 * st + i]); m = fmaxf(m, pmax[3 * st + i]);
  const float s = psum[i] * __expf(pmax[i] - m)
                + psum[st + i] * __expf(pmax[st + i] - m)
                + psum[2 * st + i] * __expf(pmax[2 * st + i] - m)
                + psum[3 * st + i] * __expf(pmax[3 * st + i] - m);
  rmax[i] = m;
  rinv[i] = 1.f / s;
}

// ---------------------------------------------------------------------------
// pass2: recompute S tile, P=exp(S-rmax)*rinv, Yt[m][c] = P^T V^T via MFMA,
// epilogue: offT[n][c] = xt[n][c] - Yt/(1e-9+colsum)  (xt buffer in-place)
__global__ __launch_bounds__(512) void pass2_mfma(
    const short* __restrict__ KT, const short* __restrict__ V,
    const float* __restrict__ rmax, const float* __restrict__ rinv,
    short* __restrict__ XO)
{
  const int m0 = blockIdx.x * 32;
  const int b  = blockIdx.y;
  const int tid = threadIdx.x;
  const int w = tid >> 6, l = tid & 63, lg = l >> 4, lr = l & 15;
  const int ni = w >> 1, msi = w & 1;

  const short* Kb = KT + (long)b * NPTS * DQ;
  const short* Vb = V  + (long)b * CO * NPTS;
  const float* rmb = rmax + (long)b * NPTS;
  const float* rib = rinv + (long)b * NPTS;

  __shared__ short Ps[32][PSTR];
  __shared__ float cspart[8][16];
  __shared__ float csum[32];

  const bf16x8 bK0 = *(const bf16x8*)&Kb[(long)(m0 + msi * 16 + lr) * DQ + lg * 8];
  const bf16x8 bK1 = *(const bf16x8*)&Kb[(long)(m0 + msi * 16 + lr) * DQ + 32 + lg * 8];

  f32x4 acc00 = {0.f,0.f,0.f,0.f}, acc01 = acc00, acc10 = acc00, acc11 = acc00;
  float cs = 0.f;
  const int c0 = w * 32;

  for (int n0 = 0; n0 < NPTS; n0 += 64) {
    const int nb = n0 + ni * 16;
    const bf16x8 a0 = *(const bf16x8*)&Kb[(long)(nb + lr) * DQ + lg * 8];
    const bf16x8 a1 = *(const bf16x8*)&Kb[(long)(nb + lr) * DQ + 32 + lg * 8];
    f32x4 s = {0.f, 0.f, 0.f, 0.f};
    s = MFMA16(a0, bK0, s);
    s = MFMA16(a1, bK1, s);
    const float4 rm4 = *(const float4*)&rmb[nb + lg * 4];
    const float4 ri4 = *(const float4*)&rib[nb + lg * 4];
    const float p0 = __expf(s[0] - rm4.x) * ri4.x;
    const float p1 = __expf(s[1] - rm4.y) * ri4.y;
    const float p2 = __expf(s[2] - rm4.z) * ri4.z;
    const float p3 = __expf(s[3] - rm4.w) * ri4.w;
    cs += p0 + p1 + p2 + p3;
    const unsigned plo = ((unsigned)(unsigned short)fb(p1) << 16) | (unsigned short)fb(p0);
    const unsigned phi = ((unsigned)(unsigned short)fb(p3) << 16) | (unsigned short)fb(p2);
    __syncthreads();   // previous PV reads of Ps complete
    *(uint2*)&Ps[msi * 16 + lr][ni * 16 + lg * 4] = make_uint2(plo, phi);
    __syncthreads();   // Ps ready
#pragma unroll
    for (int kc = 0; kc < 2; ++kc) {
      const bf16x8 pa0 = *(const bf16x8*)&Ps[lr     ][kc * 32 + lg * 8];
      const bf16x8 pa1 = *(const bf16x8*)&Ps[16 + lr][kc * 32 + lg * 8];
      const bf16x8 v0  = *(const bf16x8*)&Vb[(long)(c0      + lr) * NPTS + n0 + kc * 32 + lg * 8];
      const bf16x8 v1  = *(const bf16x8*)&Vb[(long)(c0 + 16 + lr) * NPTS + n0 + kc * 32 + lg * 8];
      acc00 = MFMA16(pa0, v0, acc00);
      acc01 = MFMA16(pa0, v1, acc01);
      acc10 = MFMA16(pa1, v0, acc10);
      acc11 = MFMA16(pa1, v1, acc11);
    }
  }

  float csv = cs;
  csv += __shfl_xor(csv, 16);
  csv += __shfl_xor(csv, 32);
  if (lg == 0) cspart[w][lr] = csv;
  __syncthreads();
  if (tid < 32) {
    const int ms = tid >> 4, cr = tid & 15;
    csum[tid] = cspart[ms][cr] + cspart[ms + 2][cr] + cspart[ms + 4][cr] + cspart[ms + 6][cr];
  }
  __syncthreads();

  short* XOb = XO + (long)b * NPTS * CO;
#pragma unroll
  for (int mi = 0; mi < 2; ++mi) {
    const f32x4 y0 = mi ? acc10 : acc00;
    const f32x4 y1 = mi ? acc11 : acc01;
#pragma unroll
    for (int j = 0; j < 4; ++j) {
      const int m = m0 + mi * 16 + lg * 4 + j;
      const float inv = 1.f / (1e-9f + csum[mi * 16 + lg * 4 + j]);
      const long i0 = (long)m * CO + c0 + lr;
      const long i1 = (long)m * CO + c0 + 16 + lr;
      XOb[i0] = fb(bf(XOb[i0]) - y0[j] * inv);
      XOb[i1] = fb(bf(XOb[i1]) - y1[j] * inv);
    }
  }
}

// ---------------------------------------------------------------------------
extern "C" void kernel_launch(void* const* d_in, const int* in_sizes, int n_in,
                              void* d_out, int out_size, void* d_ws, size_t ws_size,
                              hipStream_t stream)
{
  const float* feat = (const float*)d_in[0];
  const float* w1   = (const float*)d_in[1];
  const float* g1   = (const float*)d_in[2];
  const float* b1   = (const float*)d_in[3];
  const float* w2   = (const float*)d_in[4];
  const float* g2   = (const float*)d_in[5];
  const float* b2   = (const float*)d_in[6];
  const float* qkw  = (const float*)d_in[7];
  const float* vw   = (const float*)d_in[8];
  const float* vb   = (const float*)d_in[9];
  const float* tw   = (const float*)d_in[10];
  const float* tb   = (const float*)d_in[11];
  const float* bng  = (const float*)d_in[12];
  const float* bnb  = (const float*)d_in[13];

  float* out = (float*)d_out;

  // workspace (~19.5 MB)
  short* xt    = (short*)d_ws;                       // [B][N][CO] bf16 (xt, then offT)
  short* KTb   = xt + (long)BB * NPTS * CO;          // [B][N][DQ] bf16
  short* Vb    = KTb + (long)BB * NPTS * DQ;         // [B][CO][N] bf16
  float* pmaxb = (float*)(Vb + (long)BB * CO * NPTS);// [4][B][N]
  float* psumb = pmaxb + (long)4 * BB * NPTS;        // [4][B][N]
  float* rmaxb = psumb + (long)4 * BB * NPTS;        // [B][N]
  float* rinvb = rmaxb + (long)BB * NPTS;            // [B][N]
  float* meanb = rinvb + (long)BB * NPTS;            // [CO]
  float* rstdb = meanb + CO;                         // [CO]

  const long OBS = (long)LL * CO * NPTS;
  float* h1 = out + (long)2 * CO * NPTS;  // stem scratch in slice-2 region
  float* x0 = out + (long)1 * CO * NPTS;  // stem output in slice-1 region

  const dim3 blk(256);

  // ---- stem ----
  tcvt_k<<<dim3(64, 2, BB), blk, 0, stream>>>(feat, (long)CI * NPTS, CI, xt);
  conv_a<false,false><<<dim3(64, 4, BB), blk, 0, stream>>>(xt, CI, w1, nullptr, h1, OBS);
  bnstats_k<<<dim3(CO), blk, 0, stream>>>(h1, OBS, meanb, rstdb);
  bnrelu_k<<<dim3(2048), blk, 0, stream>>>(h1, OBS, meanb, rstdb, g1, b1, h1, OBS);
  tcvt_k<<<dim3(64, 4, BB), blk, 0, stream>>>(h1, OBS, CO, xt);
  conv_a<false,false><<<dim3(64, 4, BB), blk, 0, stream>>>(xt, CO, w2, nullptr, x0, OBS);
  bnstats_k<<<dim3(CO), blk, 0, stream>>>(x0, OBS, meanb, rstdb);
  bnrelu_k<<<dim3(2048), blk, 0, stream>>>(x0, OBS, meanb, rstdb, g2, b2, x0, OBS);

  // ---- stacked offset attention ----
  const float* x = x0;
  for (int lyr = 0; lyr < LL; ++lyr) {
    float* nft = out + (long)lyr * CO * NPTS;
    tcvt_k<<<dim3(64, 4, BB), blk, 0, stream>>>(x, OBS, CO, xt);
    conv_b<<<dim3(64, BB), blk, 0, stream>>>(xt, qkw + (long)lyr * DQ * CO, KTb);
    conv_a<true,true><<<dim3(64, 4, BB), blk, 0, stream>>>(
        xt, CO, vw + (long)lyr * CO * CO, vb + (long)lyr * CO, Vb, (long)CO * NPTS);
    rowstats_mfma<<<dim3(64, 4, BB), blk, 0, stream>>>(KTb, pmaxb, psumb);
    combine_k<<<dim3(BB * NPTS / 256), blk, 0, stream>>>(pmaxb, psumb, rmaxb, rinvb);
    pass2_mfma<<<dim3(NPTS / 32, BB), dim3(512), 0, stream>>>(KTb, Vb, rmaxb, rinvb, xt);
    conv_a<false,true><<<dim3(64, 4, BB), blk, 0, stream>>>(
        xt, CO, tw + (long)lyr * CO * CO, tb + (long)lyr * CO, nft, OBS);
    bnstats_k<<<dim3(CO), blk, 0, stream>>>(nft, OBS, meanb, rstdb);
    bnrelu_k<<<dim3(2048), blk, 0, stream>>>(
        nft, OBS, meanb, rstdb, bng + (long)lyr * CO, bnb + (long)lyr * CO, nft, OBS);
    x = nft;
  }
}

// Round 3
// 1201.126 us; speedup vs baseline: 11.9980x; 1.2470x over previous
//
#include <hip/hip_runtime.h>
#include <hip/hip_bf16.h>
#include <math.h>

#define NPTS 4096
#define CO   256
#define CI   128
#define BB   4
#define DQ   64
#define LL   4
#define PST  136   // Ps row stride in shorts (272B): lane-row stride -> 2-way bank alias only

typedef __attribute__((ext_vector_type(8))) short bf16x8;
typedef __attribute__((ext_vector_type(4))) float f32x4;

#define MFMA16(a,b,c) __builtin_amdgcn_mfma_f32_16x16x32_bf16((a),(b),(c),0,0,0)

__device__ __forceinline__ short fb(float x) {
  __hip_bfloat16 h = __float2bfloat16(x);
  return __builtin_bit_cast(short, h);
}
__device__ __forceinline__ float bf(short s) {
  unsigned u = ((unsigned)(unsigned short)s) << 16;
  return __builtin_bit_cast(float, u);
}

// ---------------------------------------------------------------------------
// generic fp32 -> bf16 convert, 8 elements/thread (counts are multiples of 8)
__global__ __launch_bounds__(256) void cvtw_k(
    const float* __restrict__ S, short* __restrict__ D, int n8)
{
  const int i = blockIdx.x * 256 + threadIdx.x;
  if (i < n8) {
    const float4 a = ((const float4*)S)[i * 2];
    const float4 b = ((const float4*)S)[i * 2 + 1];
    bf16x8 r;
    r[0] = fb(a.x); r[1] = fb(a.y); r[2] = fb(a.z); r[3] = fb(a.w);
    r[4] = fb(b.x); r[5] = fb(b.y); r[6] = fb(b.z); r[7] = fb(b.w);
    ((bf16x8*)D)[i] = r;
  }
}

// ---------------------------------------------------------------------------
// fp32 [b][C][N] -> bf16 [b][N][C] transpose-convert (stem input only)
__global__ __launch_bounds__(256) void tcvt_k(
    const float* __restrict__ X, long xbs, int C, short* __restrict__ XT)
{
  const int n0 = blockIdx.x * 64, c0 = blockIdx.y * 64, b = blockIdx.z;
  const int t = threadIdx.x, tl = t & 63, tg = t >> 6;
  __shared__ float xs[64][65];
#pragma unroll
  for (int r = 0; r < 16; ++r) {
    const int cc = tg * 16 + r;
    xs[cc][tl] = X[(long)b * xbs + (long)(c0 + cc) * NPTS + n0 + tl];
  }
  __syncthreads();
#pragma unroll
  for (int r = 0; r < 16; ++r) {
    const int nn = tg * 16 + r;
    XT[((long)b * NPTS + n0 + nn) * C + c0 + tl] = fb(xs[tl][nn]);
  }
}

// ---------------------------------------------------------------------------
// conv_a: Y[b][d][n] = sum_c Wb[d][c] * XT[b][n][c] (+bias), bf16 weights.
// n-tile 128, d-tile 64. OMODE 0: fp32 [d][N]; 1: bf16 n-blocked [n>>7][d][128]
template<int OMODE, bool BIAS>
__global__ __launch_bounds__(256) void conv_a(
    const short* __restrict__ XT, int C,
    const short* __restrict__ Wb, const float* __restrict__ bias,
    void* __restrict__ Yv, long ybs)
{
  const int n0 = blockIdx.x * 128, d0 = blockIdx.y * 64, b = blockIdx.z;
  const int tid = threadIdx.x, w = tid >> 6, l = tid & 63, lg = l >> 4, lr = l & 15;
  const short* xb = XT + (long)b * NPTS * C;
  f32x4 acc[8];
#pragma unroll
  for (int i = 0; i < 8; ++i) acc[i] = (f32x4){0.f, 0.f, 0.f, 0.f};
  const int dr = d0 + w * 16 + lr;
  for (int kc = 0; kc < C; kc += 32) {
    const bf16x8 af = *(const bf16x8*)&Wb[(long)dr * C + kc + lg * 8];
#pragma unroll
    for (int ni = 0; ni < 8; ++ni) {
      const bf16x8 bx = *(const bf16x8*)&xb[(long)(n0 + ni * 16 + lr) * C + kc + lg * 8];
      acc[ni] = MFMA16(af, bx, acc[ni]);
    }
  }
  float bv[4] = {0.f, 0.f, 0.f, 0.f};
  if (BIAS) {
    const float4 b4 = *(const float4*)&bias[d0 + w * 16 + lg * 4];
    bv[0] = b4.x; bv[1] = b4.y; bv[2] = b4.z; bv[3] = b4.w;
  }
  const int db = d0 + w * 16 + lg * 4;
#pragma unroll
  for (int ni = 0; ni < 8; ++ni) {
    const int n = n0 + ni * 16 + lr;
#pragma unroll
    for (int j = 0; j < 4; ++j) {
      const float o = acc[ni][j] + bv[j];
      if constexpr (OMODE == 0) {
        ((float*)Yv)[(long)b * ybs + (long)(db + j) * NPTS + n] = o;
      } else {
        ((short*)Yv)[(long)b * ybs + ((long)(n0 >> 7) * CO + db + j) * 128 + (n & 127)] = fb(o);
      }
    }
  }
}

// ---------------------------------------------------------------------------
// conv_b: KT[b][n][d] = sum_c XT[b][n][c] * Wb[d][c], bf16 weights, Dtot=64.
__global__ __launch_bounds__(256) void conv_b(
    const short* __restrict__ XT, const short* __restrict__ Wb,
    short* __restrict__ KTo)
{
  const int n0 = blockIdx.x * 64, b = blockIdx.y;
  const int tid = threadIdx.x, w = tid >> 6, l = tid & 63, lg = l >> 4, lr = l & 15;
  const short* xb = XT + (long)b * NPTS * CO;
  f32x4 acc[4];
#pragma unroll
  for (int i = 0; i < 4; ++i) acc[i] = (f32x4){0.f, 0.f, 0.f, 0.f};
  const long nr = n0 + w * 16 + lr;
  for (int kc = 0; kc < CO; kc += 32) {
    const bf16x8 af = *(const bf16x8*)&xb[nr * CO + kc + lg * 8];
#pragma unroll
    for (int di = 0; di < 4; ++di) {
      const bf16x8 wf = *(const bf16x8*)&Wb[(long)(di * 16 + lr) * CO + kc + lg * 8];
      acc[di] = MFMA16(af, wf, acc[di]);
    }
  }
  short* Ko = KTo + (long)b * NPTS * DQ;
  const int nb = n0 + w * 16 + lg * 4;
#pragma unroll
  for (int j = 0; j < 4; ++j) {
#pragma unroll
    for (int di = 0; di < 4; ++di)
      Ko[(long)(nb + j) * DQ + di * 16 + lr] = fb(acc[di][j]);
  }
}

// ---------------------------------------------------------------------------
// BN stats per channel over (B, N), vectorized
__global__ __launch_bounds__(256) void bnstats_k(
    const float* __restrict__ X, long xbs,
    float* __restrict__ mean, float* __restrict__ rstd)
{
  const int c = blockIdx.x, t = threadIdx.x;
  float s = 0.f, s2 = 0.f;
  for (int b = 0; b < BB; ++b) {
    const float4* p = (const float4*)(X + (long)b * xbs + (long)c * NPTS);
    for (int n = t; n < NPTS / 4; n += 256) {
      const float4 v = p[n];
      s  += v.x + v.y + v.z + v.w;
      s2 += v.x * v.x + v.y * v.y + v.z * v.z + v.w * v.w;
    }
  }
#pragma unroll
  for (int o = 32; o > 0; o >>= 1) { s += __shfl_down(s, o); s2 += __shfl_down(s2, o); }
  __shared__ float a1[4], a2[4];
  if ((t & 63) == 0) { a1[t >> 6] = s; a2[t >> 6] = s2; }
  __syncthreads();
  if (t == 0) {
    const float S  = a1[0] + a1[1] + a1[2] + a1[3];
    const float S2 = a2[0] + a2[1] + a2[2] + a2[3];
    const float m  = S / (float)(BB * NPTS);
    const float v  = S2 / (float)(BB * NPTS) - m * m;
    mean[c] = m;
    rstd[c] = rsqrtf(v + 1e-5f);
  }
}

// ---------------------------------------------------------------------------
// BN normalize + affine + ReLU, optionally writing fp32 [c][n] (in-place ok)
// and/or bf16 transpose [n][CO]
template<bool WF32, bool WBF>
__global__ __launch_bounds__(256) void bnrelu_t(
    const float* __restrict__ X, long xbs,
    const float* __restrict__ mean, const float* __restrict__ rstd,
    const float* __restrict__ g, const float* __restrict__ be,
    float* __restrict__ Yf, long ybs, short* __restrict__ XT)
{
  const int n0 = blockIdx.x * 64, c0 = blockIdx.y * 64, b = blockIdx.z;
  const int t = threadIdx.x, tl = t & 63, tg = t >> 6;
  __shared__ float xs[64][65];
#pragma unroll
  for (int r = 0; r < 16; ++r) {
    const int cc = tg * 16 + r, c = c0 + cc;
    float v = X[(long)b * xbs + (long)c * NPTS + n0 + tl];
    v = fmaxf((v - mean[c]) * rstd[c] * g[c] + be[c], 0.f);
    if (WF32) Yf[(long)b * ybs + (long)c * NPTS + n0 + tl] = v;
    xs[cc][tl] = v;
  }
  __syncthreads();
  if (WBF) {
#pragma unroll
    for (int r = 0; r < 16; ++r) {
      const int nn = tg * 16 + r;
      XT[((long)b * NPTS + n0 + nn) * CO + c0 + tl] = fb(xs[tl][nn]);
    }
  }
}

// ---------------------------------------------------------------------------
// pass1: per-row softmax stats of S = K^T K over an m-chunk (MFMA)
#define ONL(MX, SM, SV) { const float m2_ = fmaxf(MX, SV); \
  SM = SM * __expf(MX - m2_) + __expf(SV - m2_); MX = m2_; }
#define MRG(MX, SM, OFF) { const float om_ = __shfl_xor(MX, OFF); \
  const float os_ = __shfl_xor(SM, OFF); \
  const float m2_ = fmaxf(MX, om_); \
  SM = SM * __expf(MX - m2_) + os_ * __expf(om_ - m2_); MX = m2_; }

__global__ __launch_bounds__(256) void rowstats_mfma(
    const short* __restrict__ KT, float* __restrict__ pmax, float* __restrict__ psum)
{
  const int n0 = blockIdx.x * 64;
  const int chunk = blockIdx.y;
  const int b = blockIdx.z;
  const int tid = threadIdx.x, w = tid >> 6, l = tid & 63, lg = l >> 4, lr = l & 15;
  const short* Kb = KT + (long)b * NPTS * DQ;
  const int nr = n0 + w * 16 + lr;
  const bf16x8 a0 = *(const bf16x8*)&Kb[(long)nr * DQ + lg * 8];
  const bf16x8 a1 = *(const bf16x8*)&Kb[(long)nr * DQ + 32 + lg * 8];

  float mx0 = -INFINITY, mx1 = -INFINITY, mx2 = -INFINITY, mx3 = -INFINITY;
  float sm0 = 0.f, sm1 = 0.f, sm2 = 0.f, sm3 = 0.f;

  const int mc = chunk * (NPTS / 4);
  for (int m0 = mc; m0 < mc + NPTS / 4; m0 += 16) {
    const bf16x8 b0 = *(const bf16x8*)&Kb[(long)(m0 + lr) * DQ + lg * 8];
    const bf16x8 b1 = *(const bf16x8*)&Kb[(long)(m0 + lr) * DQ + 32 + lg * 8];
    f32x4 s = {0.f, 0.f, 0.f, 0.f};
    s = MFMA16(a0, b0, s);
    s = MFMA16(a1, b1, s);
    ONL(mx0, sm0, s[0]); ONL(mx1, sm1, s[1]);
    ONL(mx2, sm2, s[2]); ONL(mx3, sm3, s[3]);
  }
#pragma unroll
  for (int off = 1; off < 16; off <<= 1) {
    MRG(mx0, sm0, off); MRG(mx1, sm1, off);
    MRG(mx2, sm2, off); MRG(mx3, sm3, off);
  }
  if (lr == 0) {
    const long base = ((long)chunk * BB + b) * NPTS + n0 + w * 16 + lg * 4;
    pmax[base + 0] = mx0; pmax[base + 1] = mx1; pmax[base + 2] = mx2; pmax[base + 3] = mx3;
    psum[base + 0] = sm0; psum[base + 1] = sm1; psum[base + 2] = sm2; psum[base + 3] = sm3;
  }
}

__global__ __launch_bounds__(256) void combine_k(
    const float* __restrict__ pmax, const float* __restrict__ psum,
    float* __restrict__ rmax, float* __restrict__ rinv)
{
  const long i = (long)blockIdx.x * 256 + threadIdx.x;
  const long st = (long)BB * NPTS;
  float m = pmax[i];
  m = fmaxf(m, pmax[st + i]); m = fmaxf(m, pmax[2 * st + i]); m = fmaxf(m, pmax[3 * st + i]);
  const float s = psum[i] * __expf(pmax[i] - m)
                + psum[st + i] * __expf(pmax[st + i] - m)
                + psum[2 * st + i] * __expf(pmax[2 * st + i] - m)
                + psum[3 * st + i] * __expf(pmax[3 * st + i] - m);
  rmax[i] = m;
  rinv[i] = 1.f / s;
}

// ---------------------------------------------------------------------------
// pass2 v2: m-tile 32, n-step 128, double-buffered P, one light barrier/iter.
// V in n-blocked layout [n>>7][c][128]. Epilogue: colsum renorm + off = x - nf
// written in place into XT.
__global__ __launch_bounds__(512, 4) void pass2_mfma(
    const short* __restrict__ KT, const short* __restrict__ Vblk,
    const float* __restrict__ rmax, const float* __restrict__ rinv,
    short* __restrict__ XO)
{
  const int m0 = blockIdx.x * 32;
  const int b  = blockIdx.y;
  const int tid = threadIdx.x;
  const int w = tid >> 6, l = tid & 63, lg = l >> 4, lr = l & 15;

  const short* Kb = KT + (long)b * NPTS * DQ;
  const short* Vb = Vblk + (long)b * CO * NPTS;
  const float* rmb = rmax + (long)b * NPTS;
  const float* rib = rinv + (long)b * NPTS;

  __shared__ short Ps[2][32][PST];
  __shared__ float cspart[8][32];
  __shared__ float csum[32];

  // block-fixed K m-frags (msi 0/1 x k-chunk 0/1)
  const bf16x8 bK00 = *(const bf16x8*)&Kb[(long)(m0 + lr) * DQ + lg * 8];
  const bf16x8 bK01 = *(const bf16x8*)&Kb[(long)(m0 + lr) * DQ + 32 + lg * 8];
  const bf16x8 bK10 = *(const bf16x8*)&Kb[(long)(m0 + 16 + lr) * DQ + lg * 8];
  const bf16x8 bK11 = *(const bf16x8*)&Kb[(long)(m0 + 16 + lr) * DQ + 32 + lg * 8];

  f32x4 acc00 = {0.f,0.f,0.f,0.f}, acc01 = acc00, acc10 = acc00, acc11 = acc00;
  float cs0 = 0.f, cs1 = 0.f;
  const int c0 = w * 32;   // PV role: c-range
  const int nb = w * 16;   // S role: n-frag within 128-step

  // prologue: K n-frags for iter 0
  bf16x8 a0 = *(const bf16x8*)&Kb[(long)(nb + lr) * DQ + lg * 8];
  bf16x8 a1 = *(const bf16x8*)&Kb[(long)(nb + lr) * DQ + 32 + lg * 8];

  int buf = 0;
  for (int n0 = 0; n0 < NPTS; n0 += 128) {
    // ---- phase A: issue V loads for this iter (contiguous 8KB/wave region)
    const short* vt = Vb + (long)(n0 >> 7) * CO * 128;
    bf16x8 vf[8];
#pragma unroll
    for (int kc = 0; kc < 4; ++kc) {
      vf[kc * 2 + 0] = *(const bf16x8*)&vt[(long)(c0 + lr) * 128 + kc * 32 + lg * 8];
      vf[kc * 2 + 1] = *(const bf16x8*)&vt[(long)(c0 + 16 + lr) * 128 + kc * 32 + lg * 8];
    }
    // S frags: D[n][m] (col=m=lr, rows n=lg*4+j), n in [n0+nb, +16)
    f32x4 s0 = {0.f,0.f,0.f,0.f}, s1 = s0;
    s0 = MFMA16(a0, bK00, s0); s0 = MFMA16(a1, bK01, s0);
    s1 = MFMA16(a0, bK10, s1); s1 = MFMA16(a1, bK11, s1);
    const float4 rm4 = *(const float4*)&rmb[n0 + nb + lg * 4];
    const float4 ri4 = *(const float4*)&rib[n0 + nb + lg * 4];
    const float p00 = __expf(s0[0] - rm4.x) * ri4.x;
    const float p01 = __expf(s0[1] - rm4.y) * ri4.y;
    const float p02 = __expf(s0[2] - rm4.z) * ri4.z;
    const float p03 = __expf(s0[3] - rm4.w) * ri4.w;
    const float p10 = __expf(s1[0] - rm4.x) * ri4.x;
    const float p11 = __expf(s1[1] - rm4.y) * ri4.y;
    const float p12 = __expf(s1[2] - rm4.z) * ri4.z;
    const float p13 = __expf(s1[3] - rm4.w) * ri4.w;
    cs0 += p00 + p01 + p02 + p03;
    cs1 += p10 + p11 + p12 + p13;
    const unsigned u00 = ((unsigned)(unsigned short)fb(p01) << 16) | (unsigned short)fb(p00);
    const unsigned u01 = ((unsigned)(unsigned short)fb(p03) << 16) | (unsigned short)fb(p02);
    const unsigned u10 = ((unsigned)(unsigned short)fb(p11) << 16) | (unsigned short)fb(p10);
    const unsigned u11 = ((unsigned)(unsigned short)fb(p13) << 16) | (unsigned short)fb(p12);
    *(uint2*)&Ps[buf][lr     ][nb + lg * 4] = make_uint2(u00, u01);
    *(uint2*)&Ps[buf][16 + lr][nb + lg * 4] = make_uint2(u10, u11);
    // light barrier: wait own LDS writes only; V loads stay in flight (no vmcnt drain)
    asm volatile("s_waitcnt lgkmcnt(0)" ::: "memory");
    __builtin_amdgcn_s_barrier();
    // ---- phase B: prefetch next K n-frags, then PV MFMAs
    if (n0 + 128 < NPTS) {
      a0 = *(const bf16x8*)&Kb[(long)(n0 + 128 + nb + lr) * DQ + lg * 8];
      a1 = *(const bf16x8*)&Kb[(long)(n0 + 128 + nb + lr) * DQ + 32 + lg * 8];
    }
#pragma unroll
    for (int kc = 0; kc < 4; ++kc) {
      const bf16x8 pa0 = *(const bf16x8*)&Ps[buf][lr     ][kc * 32 + lg * 8];
      const bf16x8 pa1 = *(const bf16x8*)&Ps[buf][16 + lr][kc * 32 + lg * 8];
      acc00 = MFMA16(pa0, vf[kc * 2 + 0], acc00);
      acc01 = MFMA16(pa0, vf[kc * 2 + 1], acc01);
      acc10 = MFMA16(pa1, vf[kc * 2 + 0], acc10);
      acc11 = MFMA16(pa1, vf[kc * 2 + 1], acc11);
    }
    buf ^= 1;
  }

  // colsum: cs lanes hold m-col = lr; sum over lg groups then over waves
  float csv0 = cs0, csv1 = cs1;
  csv0 += __shfl_xor(csv0, 16); csv0 += __shfl_xor(csv0, 32);
  csv1 += __shfl_xor(csv1, 16); csv1 += __shfl_xor(csv1, 32);
  if (lg == 0) { cspart[w][lr] = csv0; cspart[w][16 + lr] = csv1; }
  __syncthreads();
  if (tid < 32) {
    float s = 0.f;
#pragma unroll
    for (int ww = 0; ww < 8; ++ww) s += cspart[ww][tid];
    csum[tid] = s;
  }
  __syncthreads();

  short* XOb = XO + (long)b * NPTS * CO;
#pragma unroll
  for (int mi = 0; mi < 2; ++mi) {
    const f32x4 y0 = mi ? acc10 : acc00;
    const f32x4 y1 = mi ? acc11 : acc01;
#pragma unroll
    for (int j = 0; j < 4; ++j) {
      const int m = m0 + mi * 16 + lg * 4 + j;
      const float inv = 1.f / (1e-9f + csum[mi * 16 + lg * 4 + j]);
      const long i0 = (long)m * CO + c0 + lr;
      const long i1 = (long)m * CO + c0 + 16 + lr;
      XOb[i0] = fb(bf(XOb[i0]) - y0[j] * inv);
      XOb[i1] = fb(bf(XOb[i1]) - y1[j] * inv);
    }
  }
}

// ---------------------------------------------------------------------------
extern "C" void kernel_launch(void* const* d_in, const int* in_sizes, int n_in,
                              void* d_out, int out_size, void* d_ws, size_t ws_size,
                              hipStream_t stream)
{
  const float* feat = (const float*)d_in[0];
  const float* w1   = (const float*)d_in[1];
  const float* g1   = (const float*)d_in[2];
  const float* b1   = (const float*)d_in[3];
  const float* w2   = (const float*)d_in[4];
  const float* g2   = (const float*)d_in[5];
  const float* b2   = (const float*)d_in[6];
  const float* qkw  = (const float*)d_in[7];
  const float* vw   = (const float*)d_in[8];
  const float* vb   = (const float*)d_in[9];
  const float* tw   = (const float*)d_in[10];
  const float* tb   = (const float*)d_in[11];
  const float* bng  = (const float*)d_in[12];
  const float* bnb  = (const float*)d_in[13];

  float* out = (float*)d_out;

  // workspace (~20 MB)
  short* xt    = (short*)d_ws;                        // [B][N][CO] bf16 (x^T, then off^T)
  short* KTb   = xt + (long)BB * NPTS * CO;           // [B][N][DQ]
  short* Vblk  = KTb + (long)BB * NPTS * DQ;          // [B][N/128][CO][128]
  short* wb1   = Vblk + (long)BB * CO * NPTS;         // CO*CI
  short* wb2   = wb1 + (long)CO * CI;                 // CO*CO
  short* wqk   = wb2 + (long)CO * CO;                 // L*DQ*CO
  short* wv    = wqk + (long)LL * DQ * CO;            // L*CO*CO
  short* wt    = wv + (long)LL * CO * CO;             // L*CO*CO
  float* pmaxb = (float*)(wt + (long)LL * CO * CO);   // [4][B][N]
  float* psumb = pmaxb + (long)4 * BB * NPTS;
  float* rmaxb = psumb + (long)4 * BB * NPTS;         // [B][N]
  float* rinvb = rmaxb + (long)BB * NPTS;
  float* meanb = rinvb + (long)BB * NPTS;             // [CO]
  float* rstdb = meanb + CO;

  const long OBS = (long)LL * CO * NPTS;
  float* h1 = out + (long)2 * CO * NPTS;  // stem scratch in slice-2 region
  float* x0 = out + (long)1 * CO * NPTS;  // stem scratch in slice-1 region

  const dim3 blk(256);

  // ---- weight pre-convert (fp32 -> bf16, once per call) ----
  cvtw_k<<<dim3((CO * CI / 8 + 255) / 256), blk, 0, stream>>>(w1, wb1, CO * CI / 8);
  cvtw_k<<<dim3((CO * CO / 8 + 255) / 256), blk, 0, stream>>>(w2, wb2, CO * CO / 8);
  cvtw_k<<<dim3((LL * DQ * CO / 8 + 255) / 256), blk, 0, stream>>>(qkw, wqk, LL * DQ * CO / 8);
  cvtw_k<<<dim3((LL * CO * CO / 8 + 255) / 256), blk, 0, stream>>>(vw, wv, LL * CO * CO / 8);
  cvtw_k<<<dim3((LL * CO * CO / 8 + 255) / 256), blk, 0, stream>>>(tw, wt, LL * CO * CO / 8);

  // ---- stem ----
  tcvt_k<<<dim3(64, 2, BB), blk, 0, stream>>>(feat, (long)CI * NPTS, CI, xt);
  conv_a<0, false><<<dim3(32, 4, BB), blk, 0, stream>>>(xt, CI, wb1, nullptr, h1, OBS);
  bnstats_k<<<dim3(CO), blk, 0, stream>>>(h1, OBS, meanb, rstdb);
  bnrelu_t<false, true><<<dim3(64, 4, BB), blk, 0, stream>>>(
      h1, OBS, meanb, rstdb, g1, b1, nullptr, 0, xt);
  conv_a<0, false><<<dim3(32, 4, BB), blk, 0, stream>>>(xt, CO, wb2, nullptr, x0, OBS);
  bnstats_k<<<dim3(CO), blk, 0, stream>>>(x0, OBS, meanb, rstdb);
  bnrelu_t<false, true><<<dim3(64, 4, BB), blk, 0, stream>>>(
      x0, OBS, meanb, rstdb, g2, b2, nullptr, 0, xt);

  // ---- stacked offset attention ----
  for (int lyr = 0; lyr < LL; ++lyr) {
    float* nft = out + (long)lyr * CO * NPTS;
    conv_b<<<dim3(64, BB), blk, 0, stream>>>(xt, wqk + (long)lyr * DQ * CO, KTb);
    conv_a<1, true><<<dim3(32, 4, BB), blk, 0, stream>>>(
        xt, CO, wv + (long)lyr * CO * CO, vb + (long)lyr * CO, Vblk, (long)CO * NPTS);
    rowstats_mfma<<<dim3(64, 4, BB), blk, 0, stream>>>(KTb, pmaxb, psumb);
    combine_k<<<dim3(BB * NPTS / 256), blk, 0, stream>>>(pmaxb, psumb, rmaxb, rinvb);
    pass2_mfma<<<dim3(NPTS / 32, BB), dim3(512), 0, stream>>>(KTb, Vblk, rmaxb, rinvb, xt);
    conv_a<0, true><<<dim3(32, 4, BB), blk, 0, stream>>>(
        xt, CO, wt + (long)lyr * CO * CO, tb + (long)lyr * CO, nft, OBS);
    bnstats_k<<<dim3(CO), blk, 0, stream>>>(nft, OBS, meanb, rstdb);
    if (lyr < LL - 1) {
      bnrelu_t<true, true><<<dim3(64, 4, BB), blk, 0, stream>>>(
          nft, OBS, meanb, rstdb, bng + (long)lyr * CO, bnb + (long)lyr * CO, nft, OBS, xt);
    } else {
      bnrelu_t<true, false><<<dim3(64, 4, BB), blk, 0, stream>>>(
          nft, OBS, meanb, rstdb, bng + (long)lyr * CO, bnb + (long)lyr * CO, nft, OBS, nullptr);
    }
  }
}

// Round 4
// 911.157 us; speedup vs baseline: 15.8163x; 1.3182x over previous
//
#include <hip/hip_runtime.h>
#include <hip/hip_bf16.h>
#include <math.h>

#define NPTS 4096
#define CO   256
#define CI   128
#define BB   4
#define DQ   64
#define LL   4
#define PST  136   // Ps row stride in shorts (272B = 68 words, 68/4=17 odd -> 2-way max on b128)

typedef __attribute__((ext_vector_type(8))) short bf16x8;
typedef __attribute__((ext_vector_type(4))) float f32x4;

#define MFMA16(a,b,c) __builtin_amdgcn_mfma_f32_16x16x32_bf16((a),(b),(c),0,0,0)

__device__ __forceinline__ short fb(float x) {
  __hip_bfloat16 h = __float2bfloat16(x);
  return __builtin_bit_cast(short, h);
}
__device__ __forceinline__ float bf(short s) {
  unsigned u = ((unsigned)(unsigned short)s) << 16;
  return __builtin_bit_cast(float, u);
}

// ---------------------------------------------------------------------------
// generic fp32 -> bf16 convert, 8 elements/thread (counts are multiples of 8)
__global__ __launch_bounds__(256) void cvtw_k(
    const float* __restrict__ S, short* __restrict__ D, int n8)
{
  const int i = blockIdx.x * 256 + threadIdx.x;
  if (i < n8) {
    const float4 a = ((const float4*)S)[i * 2];
    const float4 b = ((const float4*)S)[i * 2 + 1];
    bf16x8 r;
    r[0] = fb(a.x); r[1] = fb(a.y); r[2] = fb(a.z); r[3] = fb(a.w);
    r[4] = fb(b.x); r[5] = fb(b.y); r[6] = fb(b.z); r[7] = fb(b.w);
    ((bf16x8*)D)[i] = r;
  }
}

// ---------------------------------------------------------------------------
// fp32 [b][C][N] -> bf16 [b][N][C] transpose-convert (stem input only)
__global__ __launch_bounds__(256) void tcvt_k(
    const float* __restrict__ X, long xbs, int C, short* __restrict__ XT)
{
  const int n0 = blockIdx.x * 64, c0 = blockIdx.y * 64, b = blockIdx.z;
  const int t = threadIdx.x, tl = t & 63, tg = t >> 6;
  __shared__ float xs[64][65];
#pragma unroll
  for (int r = 0; r < 16; ++r) {
    const int cc = tg * 16 + r;
    xs[cc][tl] = X[(long)b * xbs + (long)(c0 + cc) * NPTS + n0 + tl];
  }
  __syncthreads();
#pragma unroll
  for (int r = 0; r < 16; ++r) {
    const int nn = tg * 16 + r;
    XT[((long)b * NPTS + n0 + nn) * C + c0 + tl] = fb(xs[tl][nn]);
  }
}

// ---------------------------------------------------------------------------
// conv_a: Y[b][d][n] = sum_c Wb[d][c] * XT[b][n][c] (+bias), bf16 weights.
// n-tile 128, d-tile 64. OMODE 0: fp32 [d][N]; 1: bf16 n-blocked [n>>7][d][128]
template<int OMODE, bool BIAS>
__global__ __launch_bounds__(256) void conv_a(
    const short* __restrict__ XT, int C,
    const short* __restrict__ Wb, const float* __restrict__ bias,
    void* __restrict__ Yv, long ybs)
{
  const int n0 = blockIdx.x * 128, d0 = blockIdx.y * 64, b = blockIdx.z;
  const int tid = threadIdx.x, w = tid >> 6, l = tid & 63, lg = l >> 4, lr = l & 15;
  const short* xb = XT + (long)b * NPTS * C;
  f32x4 acc[8];
#pragma unroll
  for (int i = 0; i < 8; ++i) acc[i] = (f32x4){0.f, 0.f, 0.f, 0.f};
  const int dr = d0 + w * 16 + lr;
  for (int kc = 0; kc < C; kc += 32) {
    const bf16x8 af = *(const bf16x8*)&Wb[(long)dr * C + kc + lg * 8];
#pragma unroll
    for (int ni = 0; ni < 8; ++ni) {
      const bf16x8 bx = *(const bf16x8*)&xb[(long)(n0 + ni * 16 + lr) * C + kc + lg * 8];
      acc[ni] = MFMA16(af, bx, acc[ni]);
    }
  }
  float bv[4] = {0.f, 0.f, 0.f, 0.f};
  if (BIAS) {
    const float4 b4 = *(const float4*)&bias[d0 + w * 16 + lg * 4];
    bv[0] = b4.x; bv[1] = b4.y; bv[2] = b4.z; bv[3] = b4.w;
  }
  const int db = d0 + w * 16 + lg * 4;
#pragma unroll
  for (int ni = 0; ni < 8; ++ni) {
    const int n = n0 + ni * 16 + lr;
#pragma unroll
    for (int j = 0; j < 4; ++j) {
      const float o = acc[ni][j] + bv[j];
      if constexpr (OMODE == 0) {
        ((float*)Yv)[(long)b * ybs + (long)(db + j) * NPTS + n] = o;
      } else {
        ((short*)Yv)[(long)b * ybs + ((long)(n0 >> 7) * CO + db + j) * 128 + (n & 127)] = fb(o);
      }
    }
  }
}

// ---------------------------------------------------------------------------
// conv_b: KT[b][n][d] = sum_c XT[b][n][c] * Wb[d][c], bf16 weights, Dtot=64.
__global__ __launch_bounds__(256) void conv_b(
    const short* __restrict__ XT, const short* __restrict__ Wb,
    short* __restrict__ KTo)
{
  const int n0 = blockIdx.x * 64, b = blockIdx.y;
  const int tid = threadIdx.x, w = tid >> 6, l = tid & 63, lg = l >> 4, lr = l & 15;
  const short* xb = XT + (long)b * NPTS * CO;
  f32x4 acc[4];
#pragma unroll
  for (int i = 0; i < 4; ++i) acc[i] = (f32x4){0.f, 0.f, 0.f, 0.f};
  const long nr = n0 + w * 16 + lr;
  for (int kc = 0; kc < CO; kc += 32) {
    const bf16x8 af = *(const bf16x8*)&xb[nr * CO + kc + lg * 8];
#pragma unroll
    for (int di = 0; di < 4; ++di) {
      const bf16x8 wf = *(const bf16x8*)&Wb[(long)(di * 16 + lr) * CO + kc + lg * 8];
      acc[di] = MFMA16(af, wf, acc[di]);
    }
  }
  short* Ko = KTo + (long)b * NPTS * DQ;
  const int nb = n0 + w * 16 + lg * 4;
#pragma unroll
  for (int j = 0; j < 4; ++j) {
#pragma unroll
    for (int di = 0; di < 4; ++di)
      Ko[(long)(nb + j) * DQ + di * 16 + lr] = fb(acc[di][j]);
  }
}

// ---------------------------------------------------------------------------
// BN stats per channel over (B, N), vectorized
__global__ __launch_bounds__(256) void bnstats_k(
    const float* __restrict__ X, long xbs,
    float* __restrict__ mean, float* __restrict__ rstd)
{
  const int c = blockIdx.x, t = threadIdx.x;
  float s = 0.f, s2 = 0.f;
  for (int b = 0; b < BB; ++b) {
    const float4* p = (const float4*)(X + (long)b * xbs + (long)c * NPTS);
    for (int n = t; n < NPTS / 4; n += 256) {
      const float4 v = p[n];
      s  += v.x + v.y + v.z + v.w;
      s2 += v.x * v.x + v.y * v.y + v.z * v.z + v.w * v.w;
    }
  }
#pragma unroll
  for (int o = 32; o > 0; o >>= 1) { s += __shfl_down(s, o); s2 += __shfl_down(s2, o); }
  __shared__ float a1[4], a2[4];
  if ((t & 63) == 0) { a1[t >> 6] = s; a2[t >> 6] = s2; }
  __syncthreads();
  if (t == 0) {
    const float S  = a1[0] + a1[1] + a1[2] + a1[3];
    const float S2 = a2[0] + a2[1] + a2[2] + a2[3];
    const float m  = S / (float)(BB * NPTS);
    const float v  = S2 / (float)(BB * NPTS) - m * m;
    mean[c] = m;
    rstd[c] = rsqrtf(v + 1e-5f);
  }
}

// ---------------------------------------------------------------------------
// BN normalize + affine + ReLU, optionally writing fp32 [c][n] (in-place ok)
// and/or bf16 transpose [n][CO]
template<bool WF32, bool WBF>
__global__ __launch_bounds__(256) void bnrelu_t(
    const float* __restrict__ X, long xbs,
    const float* __restrict__ mean, const float* __restrict__ rstd,
    const float* __restrict__ g, const float* __restrict__ be,
    float* __restrict__ Yf, long ybs, short* __restrict__ XT)
{
  const int n0 = blockIdx.x * 64, c0 = blockIdx.y * 64, b = blockIdx.z;
  const int t = threadIdx.x, tl = t & 63, tg = t >> 6;
  __shared__ float xs[64][65];
#pragma unroll
  for (int r = 0; r < 16; ++r) {
    const int cc = tg * 16 + r, c = c0 + cc;
    float v = X[(long)b * xbs + (long)c * NPTS + n0 + tl];
    v = fmaxf((v - mean[c]) * rstd[c] * g[c] + be[c], 0.f);
    if (WF32) Yf[(long)b * ybs + (long)c * NPTS + n0 + tl] = v;
    xs[cc][tl] = v;
  }
  __syncthreads();
  if (WBF) {
#pragma unroll
    for (int r = 0; r < 16; ++r) {
      const int nn = tg * 16 + r;
      XT[((long)b * NPTS + n0 + nn) * CO + c0 + tl] = fb(xs[tl][nn]);
    }
  }
}

// ---------------------------------------------------------------------------
// pass1: per-row softmax stats of S = K^T K over an m-chunk (MFMA).
// Flat grid, XCD-swizzled: b = (bid>>1)&3 so each batch maps to a 2-XCD pair
// and K stays L2-resident there.
#define ONL(MX, SM, SV) { const float m2_ = fmaxf(MX, SV); \
  SM = SM * __expf(MX - m2_) + __expf(SV - m2_); MX = m2_; }
#define MRG(MX, SM, OFF) { const float om_ = __shfl_xor(MX, OFF); \
  const float os_ = __shfl_xor(SM, OFF); \
  const float m2_ = fmaxf(MX, om_); \
  SM = SM * __expf(MX - m2_) + os_ * __expf(om_ - m2_); MX = m2_; }

__global__ __launch_bounds__(256) void rowstats_mfma(
    const short* __restrict__ KT, float* __restrict__ pmax, float* __restrict__ psum)
{
  const int bid = blockIdx.x;
  const int b = (bid >> 1) & 3;
  const int idx = (bid >> 3) * 2 + (bid & 1);   // 0..255
  const int n0 = (idx & 63) * 64;
  const int chunk = idx >> 6;
  const int tid = threadIdx.x, w = tid >> 6, l = tid & 63, lg = l >> 4, lr = l & 15;
  const short* Kb = KT + (long)b * NPTS * DQ;
  const int nr = n0 + w * 16 + lr;
  const bf16x8 a0 = *(const bf16x8*)&Kb[(long)nr * DQ + lg * 8];
  const bf16x8 a1 = *(const bf16x8*)&Kb[(long)nr * DQ + 32 + lg * 8];

  float mx0 = -INFINITY, mx1 = -INFINITY, mx2 = -INFINITY, mx3 = -INFINITY;
  float sm0 = 0.f, sm1 = 0.f, sm2 = 0.f, sm3 = 0.f;

  const int mc = chunk * (NPTS / 4);
  for (int m0 = mc; m0 < mc + NPTS / 4; m0 += 16) {
    const bf16x8 b0 = *(const bf16x8*)&Kb[(long)(m0 + lr) * DQ + lg * 8];
    const bf16x8 b1 = *(const bf16x8*)&Kb[(long)(m0 + lr) * DQ + 32 + lg * 8];
    f32x4 s = {0.f, 0.f, 0.f, 0.f};
    s = MFMA16(a0, b0, s);
    s = MFMA16(a1, b1, s);
    ONL(mx0, sm0, s[0]); ONL(mx1, sm1, s[1]);
    ONL(mx2, sm2, s[2]); ONL(mx3, sm3, s[3]);
  }
#pragma unroll
  for (int off = 1; off < 16; off <<= 1) {
    MRG(mx0, sm0, off); MRG(mx1, sm1, off);
    MRG(mx2, sm2, off); MRG(mx3, sm3, off);
  }
  if (lr == 0) {
    const long base = ((long)chunk * BB + b) * NPTS + n0 + w * 16 + lg * 4;
    pmax[base + 0] = mx0; pmax[base + 1] = mx1; pmax[base + 2] = mx2; pmax[base + 3] = mx3;
    psum[base + 0] = sm0; psum[base + 1] = sm1; psum[base + 2] = sm2; psum[base + 3] = sm3;
  }
}

__global__ __launch_bounds__(256) void combine_k(
    const float* __restrict__ pmax, const float* __restrict__ psum,
    float* __restrict__ rmax, float* __restrict__ rinv)
{
  const long i = (long)blockIdx.x * 256 + threadIdx.x;
  const long st = (long)BB * NPTS;
  float m = pmax[i];
  m = fmaxf(m, pmax[st + i]); m = fmaxf(m, pmax[2 * st + i]); m = fmaxf(m, pmax[3 * st + i]);
  const float s = psum[i] * __expf(pmax[i] - m)
                + psum[st + i] * __expf(pmax[st + i] - m)
                + psum[2 * st + i] * __expf(pmax[2 * st + i] - m)
                + psum[3 * st + i] * __expf(pmax[3 * st + i] - m);
  rmax[i] = m;
  rinv[i] = 1.f / s;
}

// ---------------------------------------------------------------------------
// pass2 v3: m-tile 64, n-step 128, double-buffered P, one light barrier/iter,
// XCD-swizzled so each batch's V/K/XT live in one 2-XCD L2 pair.
// Epilogue: colsum renorm + off = x - nf written in place into XT.
__global__ __launch_bounds__(512) void pass2_mfma(
    const short* __restrict__ KT, const short* __restrict__ Vblk,
    const float* __restrict__ rmax, const float* __restrict__ rinv,
    short* __restrict__ XO)
{
  const int bid = blockIdx.x;
  const int b  = (bid >> 1) & 3;
  const int m0 = ((bid >> 3) * 2 + (bid & 1)) * 64;   // 0..4032
  const int tid = threadIdx.x;
  const int w = tid >> 6, l = tid & 63, lg = l >> 4, lr = l & 15;

  const short* Kb = KT + (long)b * NPTS * DQ;
  const short* Vb = Vblk + (long)b * CO * NPTS;
  const float* rmb = rmax + (long)b * NPTS;
  const float* rib = rinv + (long)b * NPTS;

  __shared__ short Ps[2][64][PST];
  __shared__ float cspart[8][64];
  __shared__ float csum[64];

  // block-fixed K m-frags: 4 m-subtiles x 2 k-chunks
  bf16x8 bK[4][2];
#pragma unroll
  for (int ms = 0; ms < 4; ++ms) {
    bK[ms][0] = *(const bf16x8*)&Kb[(long)(m0 + ms * 16 + lr) * DQ + lg * 8];
    bK[ms][1] = *(const bf16x8*)&Kb[(long)(m0 + ms * 16 + lr) * DQ + 32 + lg * 8];
  }

  f32x4 acc[4][2];   // [m-sub][c-sub]
#pragma unroll
  for (int i = 0; i < 4; ++i) {
    acc[i][0] = (f32x4){0.f, 0.f, 0.f, 0.f};
    acc[i][1] = (f32x4){0.f, 0.f, 0.f, 0.f};
  }
  float cs[4] = {0.f, 0.f, 0.f, 0.f};
  const int c0 = w * 32;   // PV role: c-range
  const int nb = w * 16;   // S role: n-frag within 128-step

  // prologue: K n-frags + row stats for iter 0
  bf16x8 a0 = *(const bf16x8*)&Kb[(long)(nb + lr) * DQ + lg * 8];
  bf16x8 a1 = *(const bf16x8*)&Kb[(long)(nb + lr) * DQ + 32 + lg * 8];
  float4 rm4 = *(const float4*)&rmb[nb + lg * 4];
  float4 ri4 = *(const float4*)&rib[nb + lg * 4];

  int buf = 0;
  for (int n0 = 0; n0 < NPTS; n0 += 128) {
    // ---- phase A: issue V loads for this iter (contiguous 8KB/wave region)
    const short* vt = Vb + (long)(n0 >> 7) * CO * 128;
    bf16x8 vf[4][2];
#pragma unroll
    for (int kc = 0; kc < 4; ++kc) {
      vf[kc][0] = *(const bf16x8*)&vt[(long)(c0 + lr) * 128 + kc * 32 + lg * 8];
      vf[kc][1] = *(const bf16x8*)&vt[(long)(c0 + 16 + lr) * 128 + kc * 32 + lg * 8];
    }
    // S frags: D[n][m] per m-sub (col=m=lr, rows n=lg*4+j), n in [n0+nb, +16)
    f32x4 s[4];
#pragma unroll
    for (int ms = 0; ms < 4; ++ms) {
      s[ms] = (f32x4){0.f, 0.f, 0.f, 0.f};
      s[ms] = MFMA16(a0, bK[ms][0], s[ms]);
      s[ms] = MFMA16(a1, bK[ms][1], s[ms]);
    }
#pragma unroll
    for (int ms = 0; ms < 4; ++ms) {
      const float p0 = __expf(s[ms][0] - rm4.x) * ri4.x;
      const float p1 = __expf(s[ms][1] - rm4.y) * ri4.y;
      const float p2 = __expf(s[ms][2] - rm4.z) * ri4.z;
      const float p3 = __expf(s[ms][3] - rm4.w) * ri4.w;
      cs[ms] += p0 + p1 + p2 + p3;
      const unsigned u0 = ((unsigned)(unsigned short)fb(p1) << 16) | (unsigned short)fb(p0);
      const unsigned u1 = ((unsigned)(unsigned short)fb(p3) << 16) | (unsigned short)fb(p2);
      *(uint2*)&Ps[buf][ms * 16 + lr][nb + lg * 4] = make_uint2(u0, u1);
    }
    // light barrier: wait own LDS writes only; V loads stay in flight
    asm volatile("s_waitcnt lgkmcnt(0)" ::: "memory");
    __builtin_amdgcn_s_barrier();
    // ---- phase B: prefetch next iter's K n-frags + row stats, then PV MFMAs
    if (n0 + 128 < NPTS) {
      a0 = *(const bf16x8*)&Kb[(long)(n0 + 128 + nb + lr) * DQ + lg * 8];
      a1 = *(const bf16x8*)&Kb[(long)(n0 + 128 + nb + lr) * DQ + 32 + lg * 8];
      rm4 = *(const float4*)&rmb[n0 + 128 + nb + lg * 4];
      ri4 = *(const float4*)&rib[n0 + 128 + nb + lg * 4];
    }
#pragma unroll
    for (int kc = 0; kc < 4; ++kc) {
      bf16x8 pa[4];
#pragma unroll
      for (int ms = 0; ms < 4; ++ms)
        pa[ms] = *(const bf16x8*)&Ps[buf][ms * 16 + lr][kc * 32 + lg * 8];
#pragma unroll
      for (int ms = 0; ms < 4; ++ms) {
        acc[ms][0] = MFMA16(pa[ms], vf[kc][0], acc[ms][0]);
        acc[ms][1] = MFMA16(pa[ms], vf[kc][1], acc[ms][1]);
      }
    }
    buf ^= 1;
  }

  // colsum: lane (lg,lr) of wave w holds partials for column ms*16+lr
  __syncthreads();
#pragma unroll
  for (int ms = 0; ms < 4; ++ms) {
    float csv = cs[ms];
    csv += __shfl_xor(csv, 16); csv += __shfl_xor(csv, 32);
    if (lg == 0) cspart[w][ms * 16 + lr] = csv;
  }
  __syncthreads();
  if (tid < 64) {
    float s = 0.f;
#pragma unroll
    for (int ww = 0; ww < 8; ++ww) s += cspart[ww][tid];
    csum[tid] = s;
  }
  __syncthreads();

  short* XOb = XO + (long)b * NPTS * CO;
#pragma unroll
  for (int ms = 0; ms < 4; ++ms) {
#pragma unroll
    for (int j = 0; j < 4; ++j) {
      const int m = m0 + ms * 16 + lg * 4 + j;
      const float inv = 1.f / (1e-9f + csum[ms * 16 + lg * 4 + j]);
      const long i0 = (long)m * CO + c0 + lr;
      const long i1 = (long)m * CO + c0 + 16 + lr;
      XOb[i0] = fb(bf(XOb[i0]) - acc[ms][0][j] * inv);
      XOb[i1] = fb(bf(XOb[i1]) - acc[ms][1][j] * inv);
    }
  }
}

// ---------------------------------------------------------------------------
extern "C" void kernel_launch(void* const* d_in, const int* in_sizes, int n_in,
                              void* d_out, int out_size, void* d_ws, size_t ws_size,
                              hipStream_t stream)
{
  const float* feat = (const float*)d_in[0];
  const float* w1   = (const float*)d_in[1];
  const float* g1   = (const float*)d_in[2];
  const float* b1   = (const float*)d_in[3];
  const float* w2   = (const float*)d_in[4];
  const float* g2   = (const float*)d_in[5];
  const float* b2   = (const float*)d_in[6];
  const float* qkw  = (const float*)d_in[7];
  const float* vw   = (const float*)d_in[8];
  const float* vb   = (const float*)d_in[9];
  const float* tw   = (const float*)d_in[10];
  const float* tb   = (const float*)d_in[11];
  const float* bng  = (const float*)d_in[12];
  const float* bnb  = (const float*)d_in[13];

  float* out = (float*)d_out;

  // workspace (~20 MB)
  short* xt    = (short*)d_ws;                        // [B][N][CO] bf16 (x^T, then off^T)
  short* KTb   = xt + (long)BB * NPTS * CO;           // [B][N][DQ]
  short* Vblk  = KTb + (long)BB * NPTS * DQ;          // [B][N/128][CO][128]
  short* wb1   = Vblk + (long)BB * CO * NPTS;         // CO*CI
  short* wb2   = wb1 + (long)CO * CI;                 // CO*CO
  short* wqk   = wb2 + (long)CO * CO;                 // L*DQ*CO
  short* wv    = wqk + (long)LL * DQ * CO;            // L*CO*CO
  short* wt    = wv + (long)LL * CO * CO;             // L*CO*CO
  float* pmaxb = (float*)(wt + (long)LL * CO * CO);   // [4][B][N]
  float* psumb = pmaxb + (long)4 * BB * NPTS;
  float* rmaxb = psumb + (long)4 * BB * NPTS;         // [B][N]
  float* rinvb = rmaxb + (long)BB * NPTS;
  float* meanb = rinvb + (long)BB * NPTS;             // [CO]
  float* rstdb = meanb + CO;

  const long OBS = (long)LL * CO * NPTS;
  float* h1 = out + (long)2 * CO * NPTS;  // stem scratch in slice-2 region
  float* x0 = out + (long)1 * CO * NPTS;  // stem scratch in slice-1 region

  const dim3 blk(256);

  // ---- weight pre-convert (fp32 -> bf16, once per call) ----
  cvtw_k<<<dim3((CO * CI / 8 + 255) / 256), blk, 0, stream>>>(w1, wb1, CO * CI / 8);
  cvtw_k<<<dim3((CO * CO / 8 + 255) / 256), blk, 0, stream>>>(w2, wb2, CO * CO / 8);
  cvtw_k<<<dim3((LL * DQ * CO / 8 + 255) / 256), blk, 0, stream>>>(qkw, wqk, LL * DQ * CO / 8);
  cvtw_k<<<dim3((LL * CO * CO / 8 + 255) / 256), blk, 0, stream>>>(vw, wv, LL * CO * CO / 8);
  cvtw_k<<<dim3((LL * CO * CO / 8 + 255) / 256), blk, 0, stream>>>(tw, wt, LL * CO * CO / 8);

  // ---- stem ----
  tcvt_k<<<dim3(64, 2, BB), blk, 0, stream>>>(feat, (long)CI * NPTS, CI, xt);
  conv_a<0, false><<<dim3(32, 4, BB), blk, 0, stream>>>(xt, CI, wb1, nullptr, h1, OBS);
  bnstats_k<<<dim3(CO), blk, 0, stream>>>(h1, OBS, meanb, rstdb);
  bnrelu_t<false, true><<<dim3(64, 4, BB), blk, 0, stream>>>(
      h1, OBS, meanb, rstdb, g1, b1, nullptr, 0, xt);
  conv_a<0, false><<<dim3(32, 4, BB), blk, 0, stream>>>(xt, CO, wb2, nullptr, x0, OBS);
  bnstats_k<<<dim3(CO), blk, 0, stream>>>(x0, OBS, meanb, rstdb);
  bnrelu_t<false, true><<<dim3(64, 4, BB), blk, 0, stream>>>(
      x0, OBS, meanb, rstdb, g2, b2, nullptr, 0, xt);

  // ---- stacked offset attention ----
  for (int lyr = 0; lyr < LL; ++lyr) {
    float* nft = out + (long)lyr * CO * NPTS;
    conv_b<<<dim3(64, BB), blk, 0, stream>>>(xt, wqk + (long)lyr * DQ * CO, KTb);
    conv_a<1, true><<<dim3(32, 4, BB), blk, 0, stream>>>(
        xt, CO, wv + (long)lyr * CO * CO, vb + (long)lyr * CO, Vblk, (long)CO * NPTS);
    rowstats_mfma<<<dim3(1024), blk, 0, stream>>>(KTb, pmaxb, psumb);
    combine_k<<<dim3(BB * NPTS / 256), blk, 0, stream>>>(pmaxb, psumb, rmaxb, rinvb);
    pass2_mfma<<<dim3(256), dim3(512), 0, stream>>>(KTb, Vblk, rmaxb, rinvb, xt);
    conv_a<0, true><<<dim3(32, 4, BB), blk, 0, stream>>>(
        xt, CO, wt + (long)lyr * CO * CO, tb + (long)lyr * CO, nft, OBS);
    bnstats_k<<<dim3(CO), blk, 0, stream>>>(nft, OBS, meanb, rstdb);
    if (lyr < LL - 1) {
      bnrelu_t<true, true><<<dim3(64, 4, BB), blk, 0, stream>>>(
          nft, OBS, meanb, rstdb, bng + (long)lyr * CO, bnb + (long)lyr * CO, nft, OBS, xt);
    } else {
      bnrelu_t<true, false><<<dim3(64, 4, BB), blk, 0, stream>>>(
          nft, OBS, meanb, rstdb, bng + (long)lyr * CO, bnb + (long)lyr * CO, nft, OBS, nullptr);
    }
  }
}